// Round 6
// baseline (509.576 us; speedup 1.0000x reference)
//
#include <hip/hip_runtime.h>
#include <cstdint>
#include <cstddef>

#define IN_F 8192
#define OUT_F 8192
#define BATCH 512
#define KSPLIT 4
#define KSLICE (IN_F / KSPLIT) /* 2048 */
#define BK 64
#define NIT (KSLICE / BK) /* 32 */

typedef __bf16 bf16x8 __attribute__((ext_vector_type(8)));
typedef float floatx4 __attribute__((ext_vector_type(4)));

// fp32 -> bf16 round-to-nearest-even
__device__ __forceinline__ ushort f2bf(float f) {
  uint32_t u = __float_as_uint(f);
  u += 0x7FFFu + ((u >> 16) & 1u);
  return (ushort)(u >> 16);
}

__device__ __forceinline__ uint32_t perm(uint32_t a, uint32_t b, uint32_t s) {
  return __builtin_amdgcn_perm(a, b, s);
}

// gather low bytes of 4 int32 -> one dword [x0,y0,z0,w0]
__device__ __forceinline__ uint32_t low4(const int4 p) {
  uint32_t qa = perm((uint32_t)p.y, (uint32_t)p.x, 0x00000400u);
  uint32_t qb = perm((uint32_t)p.w, (uint32_t)p.z, 0x00000400u);
  return perm(qb, qa, 0x05040100u);
}

// compact nibble dword (4 bytes, each: hi nibble = even k, lo = odd k) ->
// bf16x8 of biased weights (q+136): 0x4300|n == bf16(128+n) exactly.
__device__ __forceinline__ bf16x8 unpack8(uint32_t u) {
  uint32_t hi = (u >> 4) & 0x0F0F0F0Fu;
  uint32_t lo = u & 0x0F0F0F0Fu;
  uint32_t hl0 = perm(hi, lo, 0x01050004u);  // [h0,l0,h1,l1]
  uint32_t hl1 = perm(hi, lo, 0x03070206u);  // [h2,l2,h3,l3]
  const uint32_t c43 = 0x43434343u;
  uint4 d;
  d.x = perm(hl0, c43, 0x00050004u);
  d.y = perm(hl0, c43, 0x00070006u);
  d.z = perm(hl1, c43, 0x00050004u);
  d.w = perm(hl1, c43, 0x00070006u);
  union { uint4 u4; bf16x8 v; } cv;
  cv.u4 = d;
  return cv.v;
}

// Pass 1a: x fp32 -> bf16, plus per-slice rowsums of the converted values.
__global__ __launch_bounds__(256) void cvt_rowsum(const float* __restrict__ x,
                                                  ushort* __restrict__ xb,
                                                  float* __restrict__ rowsum) {
  const int b = blockIdx.x;
  const int t = threadIdx.x;
  const float4* xr = (const float4*)(x + (size_t)b * IN_F);
  ushort4* xo = (ushort4*)(xb + (size_t)b * IN_F);
  float s[4] = {0.f, 0.f, 0.f, 0.f};
#pragma unroll
  for (int i = 0; i < 8; ++i) {
    float4 v = xr[i * 256 + t];
    ushort4 o;
    o.x = f2bf(v.x); o.y = f2bf(v.y); o.z = f2bf(v.z); o.w = f2bf(v.w);
    xo[i * 256 + t] = o;
    s[i >> 1] += __uint_as_float((uint32_t)o.x << 16) + __uint_as_float((uint32_t)o.y << 16)
               + __uint_as_float((uint32_t)o.z << 16) + __uint_as_float((uint32_t)o.w << 16);
  }
  __shared__ float red[4][4];
  const int lane = t & 63, wid = t >> 6;
#pragma unroll
  for (int j = 0; j < 4; ++j) {
    float v = s[j];
#pragma unroll
    for (int off = 32; off >= 1; off >>= 1) v += __shfl_down(v, off, 64);
    if (lane == 0) red[wid][j] = v;
  }
  __syncthreads();
  if (t < 4) rowsum[t * BATCH + b] = red[0][t] + red[1][t] + red[2][t] + red[3][t];
}

// Pass 1b: compact packed_weight (one meaningful byte per int32, 134 MB)
// into dense nibble-bytes (33.5 MB). Pure streaming, BW-bound.
__global__ __launch_bounds__(256) void bcompact(const int* __restrict__ pw,
                                                int4* __restrict__ bc) {
  const int g = blockIdx.x * 256 + threadIdx.x;  // 524288 threads
#pragma unroll
  for (int i = 0; i < 4; ++i) {
    const size_t p = (size_t)g + (size_t)i * 524288;
    const int4* src = (const int4*)(pw + p * 16);
    int4 a = src[0], b = src[1], c = src[2], d = src[3];
    int4 o;
    o.x = (int)low4(a); o.y = (int)low4(b); o.z = (int)low4(c); o.w = (int)low4(d);
    bc[p] = o;
  }
}

// Split-K quantized GEMM on compact B. 128x128xKSLICE per block, 4 waves of
// 64x64, BK=64, 16x16x32 bf16 MFMA. Register-staged pipeline (no
// global_load_lds): loads(it+1) -> reg bufs issued BEFORE ds_writes(it), so
// the barrier drains only lgkm; vmcnt waits attach to next iter's ds_write,
// one full phase after issue. All LDS mappings bank-balanced:
//   A slot = chunk ^ (row&7)      (reads & writes 8 lanes/4-bank window)
//   B slot = chunk ^ ((row>>2)&1) (reads exactly 2 lanes/bank)
__global__ __launch_bounds__(256, 3) void qgemm(const ushort* __restrict__ xb,
                                                const char* __restrict__ bc,
                                                const float* __restrict__ scale,
                                                const float* __restrict__ rowsum,
                                                float* __restrict__ out) {
  __shared__ __align__(16) char Asm[2][16384];  // 128 rows x 128B (64 bf16)
  __shared__ __align__(16) char Bsm[2][4096];   // 128 rows x 32B compact

  const int tid = threadIdx.x;
  const int lane = tid & 63;
  const int w = tid >> 6;
  const int wm = w & 1, wn = w >> 1;
  const int lr = lane & 15, lq = lane >> 4;

  const int n0 = blockIdx.x * 128;
  const int m0 = blockIdx.y * 128;
  const int ks = blockIdx.z;

  // ---- staging: thread t -> row r = t>>1, half h = t&1 ----
  const int r = tid >> 1, h = tid & 1;
  const char* aG = (const char*)xb + (size_t)(m0 + r) * (IN_F * 2) + ks * (KSLICE * 2) + h * 64;
  const char* bG = bc + (size_t)(n0 + r) * (IN_F / 2) + ks * (KSLICE / 2) + h * 16;

  int aWoff[4];
#pragma unroll
  for (int j = 0; j < 4; ++j)
    aWoff[j] = r * 128 + (((h * 4 + j) ^ (r & 7)) * 16);
  const int bWoff = r * 32 + ((h ^ ((r >> 2) & 1)) * 16);

  // ---- frag read bases ----
  const int aRbase = (wm * 64 + lr) * 128;                 // + mi*2048 + slot*16
  const int bRbase = (wn * 64 + lr) * 32 + lq * 4;         // + ni*512 + slot*16
  const int bSel = (lr >> 2) & 1;

  floatx4 acc[4][4] = {};

  // prologue: tile 0 into reg buf 0
  int4 pa[2][4];
  int4 pb[2];
#pragma unroll
  for (int j = 0; j < 4; ++j) pa[0][j] = *(const int4*)(aG + j * 16);
  pb[0] = *(const int4*)(bG);

#pragma unroll 2
  for (int it = 0; it < NIT; ++it) {
    const int c = it & 1, nc = c ^ 1;
    // issue loads for tile(it+1) first -- in flight across write+barrier+compute
    if (it + 1 < NIT) {
      const char* ag = aG + (it + 1) * (BK * 2);
#pragma unroll
      for (int j = 0; j < 4; ++j) pa[nc][j] = *(const int4*)(ag + j * 16);
      pb[nc] = *(const int4*)(bG + (it + 1) * (BK / 2));
    }
    // stage tile(it) regs -> LDS (vmcnt wait here is for loads issued last iter)
#pragma unroll
    for (int j = 0; j < 4; ++j)
      *(int4*)(Asm[c] + aWoff[j]) = pa[c][j];
    *(int4*)(Bsm[c] + bWoff) = pb[c];
    __syncthreads();  // lgkm drain only; plain VGPR loads stay in flight
    // compute tile(it)
#pragma unroll
    for (int kk = 0; kk < 2; ++kk) {
      bf16x8 av[4], bv[4];
      const int pc = ((kk * 4 + lq) ^ (lr & 7)) * 16;
#pragma unroll
      for (int mi = 0; mi < 4; ++mi)
        av[mi] = *(const bf16x8*)(Asm[c] + aRbase + mi * 2048 + pc);
      const int bslot = (kk ^ bSel) * 16;
#pragma unroll
      for (int ni = 0; ni < 4; ++ni)
        bv[ni] = unpack8(*(const uint32_t*)(Bsm[c] + bRbase + ni * 512 + bslot));
#pragma unroll
      for (int mi = 0; mi < 4; ++mi)
#pragma unroll
        for (int ni = 0; ni < 4; ++ni)
          acc[mi][ni] = __builtin_amdgcn_mfma_f32_16x16x32_bf16(av[mi], bv[ni],
                                                                acc[mi][ni], 0, 0, 0);
    }
  }

  // epilogue: C/D layout col=lane&15, row=(lane>>4)*4+reg
  const int om = m0 + wm * 64 + lq * 4;
  const int on = n0 + wn * 64 + lr;
  float scv[4];
#pragma unroll
  for (int ni = 0; ni < 4; ++ni) scv[ni] = scale[on + ni * 16];
  float rsv[4][4];
#pragma unroll
  for (int mi = 0; mi < 4; ++mi)
#pragma unroll
    for (int rr = 0; rr < 4; ++rr)
      rsv[mi][rr] = rowsum[ks * BATCH + om + mi * 16 + rr];

#pragma unroll
  for (int mi = 0; mi < 4; ++mi)
#pragma unroll
    for (int ni = 0; ni < 4; ++ni) {
      const float s = scv[ni];
      float* op = out + (size_t)(om + mi * 16) * OUT_F + (on + ni * 16);
#pragma unroll
      for (int rr = 0; rr < 4; ++rr)
        atomicAdd(op + (size_t)rr * OUT_F, s * (acc[mi][ni][rr] - 136.f * rsv[mi][rr]));
    }
}

extern "C" void kernel_launch(void* const* d_in, const int* in_sizes, int n_in,
                              void* d_out, int out_size, void* d_ws, size_t ws_size,
                              hipStream_t stream) {
  const float* x = (const float*)d_in[0];
  const int* pw = (const int*)d_in[1];
  const float* scale = (const float*)d_in[2];
  float* out = (float*)d_out;

  // ws layout: [0,8M) xb bf16 ; [8M,+8K) rowsum ; [16M,+33.5M) compact B
  ushort* xb = (ushort*)d_ws;
  float* rowsum = (float*)((char*)d_ws + (8u << 20));
  char* bc = (char*)d_ws + (16u << 20);

  cvt_rowsum<<<BATCH, 256, 0, stream>>>(x, xb, rowsum);
  bcompact<<<2048, 256, 0, stream>>>(pw, (int4*)bc);
  hipMemsetAsync(out, 0, (size_t)out_size * sizeof(float), stream);
  dim3 grid(OUT_F / 128, BATCH / 128, KSPLIT);
  qgemm<<<grid, 256, 0, stream>>>(xb, bc, scale, rowsum, out);
}

// Round 7
// 368.786 us; speedup vs baseline: 1.3818x; 1.3818x over previous
//
#include <hip/hip_runtime.h>
#include <cstdint>
#include <cstddef>

#define IN_F 8192
#define OUT_F 8192
#define BATCH 512
#define KSPLIT 4
#define KSLICE (IN_F / KSPLIT) /* 2048 */
#define BK 64
#define NIT (KSLICE / BK) /* 32 */

typedef __bf16 bf16x8 __attribute__((ext_vector_type(8)));
typedef float floatx4 __attribute__((ext_vector_type(4)));

// fp32 -> bf16 round-to-nearest-even
__device__ __forceinline__ ushort f2bf(float f) {
  uint32_t u = __float_as_uint(f);
  u += 0x7FFFu + ((u >> 16) & 1u);
  return (ushort)(u >> 16);
}

__device__ __forceinline__ uint32_t perm(uint32_t a, uint32_t b, uint32_t s) {
  return __builtin_amdgcn_perm(a, b, s);
}

// gather low bytes of 4 int32 -> one dword [x0,y0,z0,w0]
__device__ __forceinline__ uint32_t low4(const int4 p) {
  uint32_t qa = perm((uint32_t)p.y, (uint32_t)p.x, 0x00000400u);
  uint32_t qb = perm((uint32_t)p.w, (uint32_t)p.z, 0x00000400u);
  return perm(qb, qa, 0x05040100u);
}

// compact nibble dword (4 bytes, each: hi nibble = even k, lo = odd k) ->
// bf16x8 of biased weights (q+136): 0x4300|n == bf16(128+n) exactly.
__device__ __forceinline__ bf16x8 unpack8(uint32_t u) {
  uint32_t hi = (u >> 4) & 0x0F0F0F0Fu;
  uint32_t lo = u & 0x0F0F0F0Fu;
  uint32_t hl0 = perm(hi, lo, 0x01050004u);  // [h0,l0,h1,l1]
  uint32_t hl1 = perm(hi, lo, 0x03070206u);  // [h2,l2,h3,l3]
  const uint32_t c43 = 0x43434343u;
  uint4 d;
  d.x = perm(hl0, c43, 0x00050004u);
  d.y = perm(hl0, c43, 0x00070006u);
  d.z = perm(hl1, c43, 0x00050004u);
  d.w = perm(hl1, c43, 0x00070006u);
  union { uint4 u4; bf16x8 v; } cv;
  cv.u4 = d;
  return cv.v;
}

// Pass 1a: x fp32 -> bf16, plus per-slice rowsums of the converted values.
__global__ __launch_bounds__(256) void cvt_rowsum(const float* __restrict__ x,
                                                  ushort* __restrict__ xb,
                                                  float* __restrict__ rowsum) {
  const int b = blockIdx.x;
  const int t = threadIdx.x;
  const float4* xr = (const float4*)(x + (size_t)b * IN_F);
  ushort4* xo = (ushort4*)(xb + (size_t)b * IN_F);
  float s[4] = {0.f, 0.f, 0.f, 0.f};
#pragma unroll
  for (int i = 0; i < 8; ++i) {
    float4 v = xr[i * 256 + t];
    ushort4 o;
    o.x = f2bf(v.x); o.y = f2bf(v.y); o.z = f2bf(v.z); o.w = f2bf(v.w);
    xo[i * 256 + t] = o;
    s[i >> 1] += __uint_as_float((uint32_t)o.x << 16) + __uint_as_float((uint32_t)o.y << 16)
               + __uint_as_float((uint32_t)o.z << 16) + __uint_as_float((uint32_t)o.w << 16);
  }
  __shared__ float red[4][4];
  const int lane = t & 63, wid = t >> 6;
#pragma unroll
  for (int j = 0; j < 4; ++j) {
    float v = s[j];
#pragma unroll
    for (int off = 32; off >= 1; off >>= 1) v += __shfl_down(v, off, 64);
    if (lane == 0) red[wid][j] = v;
  }
  __syncthreads();
  if (t < 4) rowsum[t * BATCH + b] = red[0][t] + red[1][t] + red[2][t] + red[3][t];
}

// Pass 1b: compact packed_weight (one meaningful byte per int32, 134 MB)
// into dense nibble-bytes (33.5 MB). Pure streaming, BW-bound.
__global__ __launch_bounds__(256) void bcompact(const int* __restrict__ pw,
                                                int4* __restrict__ bc) {
  const int g = blockIdx.x * 256 + threadIdx.x;  // 524288 threads
#pragma unroll
  for (int i = 0; i < 4; ++i) {
    const size_t p = (size_t)g + (size_t)i * 524288;
    const int4* src = (const int4*)(pw + p * 16);
    int4 a = src[0], b = src[1], c = src[2], d = src[3];
    int4 o;
    o.x = (int)low4(a); o.y = (int)low4(b); o.z = (int)low4(c); o.w = (int)low4(d);
    bc[p] = o;
  }
}

// compute one BK=64 tile from LDS buffers (all offsets precomputed)
__device__ __forceinline__ void compute_tile(const char* As, const char* Bs,
                                             int aRbase, int bRbase, int bSel,
                                             int lq, int lr7, floatx4 (*acc)[4]) {
#pragma unroll
  for (int kk = 0; kk < 2; ++kk) {
    bf16x8 av[4], bv[4];
    const int pc = ((kk * 4 + lq) ^ lr7) * 16;
#pragma unroll
    for (int mi = 0; mi < 4; ++mi)
      av[mi] = *(const bf16x8*)(As + aRbase + mi * 2048 + pc);
    const int bslot = (kk ^ bSel) * 16;
#pragma unroll
    for (int ni = 0; ni < 4; ++ni)
      bv[ni] = unpack8(*(const uint32_t*)(Bs + bRbase + ni * 512 + bslot));
#pragma unroll
    for (int mi = 0; mi < 4; ++mi)
#pragma unroll
      for (int ni = 0; ni < 4; ++ni)
        acc[mi][ni] = __builtin_amdgcn_mfma_f32_16x16x32_bf16(av[mi], bv[ni],
                                                              acc[mi][ni], 0, 0, 0);
  }
}

// Split-K quantized GEMM on compact B. 128x128xKSLICE per block, 4 waves of
// 64x64, BK=64. Register-staged pipeline with NAMED scalar double-buffer
// (R6's array version was demoted to scratch -> 536 MB spill traffic).
// Loads(it+1) issue before ds_writes(it); the barrier drains lgkm only.
// LDS swizzles (verified by SQ_LDS_BANK_CONFLICT drop in R6):
//   A slot = chunk ^ (row&7); B slot = chunk ^ ((row>>2)&1).
__global__ __launch_bounds__(256, 3) void qgemm(const ushort* __restrict__ xb,
                                                const char* __restrict__ bc,
                                                const float* __restrict__ scale,
                                                const float* __restrict__ rowsum,
                                                float* __restrict__ out) {
  __shared__ __align__(16) char Asm0[16384], Asm1[16384];  // 128 rows x 128B
  __shared__ __align__(16) char Bsm0[4096],  Bsm1[4096];   // 128 rows x 32B

  const int tid = threadIdx.x;
  const int lane = tid & 63;
  const int w = tid >> 6;
  const int wm = w & 1, wn = w >> 1;
  const int lr = lane & 15, lq = lane >> 4;
  const int lr7 = lr & 7;

  const int n0 = blockIdx.x * 128;
  const int m0 = blockIdx.y * 128;
  const int ks = blockIdx.z;

  // staging: thread t -> row r = t>>1, half h = t&1
  const int r = tid >> 1, h = tid & 1;
  const char* aG = (const char*)xb + (size_t)(m0 + r) * (IN_F * 2) + ks * (KSLICE * 2) + h * 64;
  const char* bG = bc + (size_t)(n0 + r) * (IN_F / 2) + ks * (KSLICE / 2) + h * 16;

  const int aW0 = r * 128 + (((h * 4 + 0) ^ (r & 7)) * 16);
  const int aW1 = r * 128 + (((h * 4 + 1) ^ (r & 7)) * 16);
  const int aW2 = r * 128 + (((h * 4 + 2) ^ (r & 7)) * 16);
  const int aW3 = r * 128 + (((h * 4 + 3) ^ (r & 7)) * 16);
  const int bWoff = r * 32 + ((h ^ ((r >> 2) & 1)) * 16);

  const int aRbase = (wm * 64 + lr) * 128;          // + mi*2048 + slot*16
  const int bRbase = (wn * 64 + lr) * 32 + lq * 4;  // + ni*512 + slot*16
  const int bSel = (lr >> 2) & 1;

  floatx4 acc[4][4] = {};

  // named double-buffer registers (NO arrays -> no scratch demotion)
  int4 pa0, pa1, pa2, pa3, pb;
  int4 qa0, qa1, qa2, qa3, qb;

  // prologue: tile 0 -> p
  pa0 = *(const int4*)(aG + 0);
  pa1 = *(const int4*)(aG + 16);
  pa2 = *(const int4*)(aG + 32);
  pa3 = *(const int4*)(aG + 48);
  pb = *(const int4*)(bG);

  for (int it = 0; it < NIT; it += 2) {
    // ---- phase 0: tile(it) from p into buf0; prefetch tile(it+1) -> q ----
    {
      const char* ag = aG + (it + 1) * (BK * 2);
      qa0 = *(const int4*)(ag + 0);
      qa1 = *(const int4*)(ag + 16);
      qa2 = *(const int4*)(ag + 32);
      qa3 = *(const int4*)(ag + 48);
      qb = *(const int4*)(bG + (it + 1) * (BK / 2));
    }
    *(int4*)(Asm0 + aW0) = pa0;
    *(int4*)(Asm0 + aW1) = pa1;
    *(int4*)(Asm0 + aW2) = pa2;
    *(int4*)(Asm0 + aW3) = pa3;
    *(int4*)(Bsm0 + bWoff) = pb;
    __syncthreads();
    compute_tile(Asm0, Bsm0, aRbase, bRbase, bSel, lq, lr7, acc);

    // ---- phase 1: tile(it+1) from q into buf1; prefetch tile(it+2) -> p ----
    if (it + 2 < NIT) {
      const char* ag = aG + (it + 2) * (BK * 2);
      pa0 = *(const int4*)(ag + 0);
      pa1 = *(const int4*)(ag + 16);
      pa2 = *(const int4*)(ag + 32);
      pa3 = *(const int4*)(ag + 48);
      pb = *(const int4*)(bG + (it + 2) * (BK / 2));
    }
    *(int4*)(Asm1 + aW0) = qa0;
    *(int4*)(Asm1 + aW1) = qa1;
    *(int4*)(Asm1 + aW2) = qa2;
    *(int4*)(Asm1 + aW3) = qa3;
    *(int4*)(Bsm1 + bWoff) = qb;
    __syncthreads();
    compute_tile(Asm1, Bsm1, aRbase, bRbase, bSel, lq, lr7, acc);
  }

  // epilogue: C/D layout col=lane&15, row=(lane>>4)*4+reg
  const int om = m0 + wm * 64 + lq * 4;
  const int on = n0 + wn * 64 + lr;
  float scv[4];
#pragma unroll
  for (int ni = 0; ni < 4; ++ni) scv[ni] = scale[on + ni * 16];
  float rsv[4][4];
#pragma unroll
  for (int mi = 0; mi < 4; ++mi)
#pragma unroll
    for (int rr = 0; rr < 4; ++rr)
      rsv[mi][rr] = rowsum[ks * BATCH + om + mi * 16 + rr];

#pragma unroll
  for (int mi = 0; mi < 4; ++mi)
#pragma unroll
    for (int ni = 0; ni < 4; ++ni) {
      const float s = scv[ni];
      float* op = out + (size_t)(om + mi * 16) * OUT_F + (on + ni * 16);
#pragma unroll
      for (int rr = 0; rr < 4; ++rr)
        atomicAdd(op + (size_t)rr * OUT_F, s * (acc[mi][ni][rr] - 136.f * rsv[mi][rr]));
    }
}

extern "C" void kernel_launch(void* const* d_in, const int* in_sizes, int n_in,
                              void* d_out, int out_size, void* d_ws, size_t ws_size,
                              hipStream_t stream) {
  const float* x = (const float*)d_in[0];
  const int* pw = (const int*)d_in[1];
  const float* scale = (const float*)d_in[2];
  float* out = (float*)d_out;

  // ws layout: [0,8M) xb bf16 ; [8M,+8K) rowsum ; [16M,+33.5M) compact B
  ushort* xb = (ushort*)d_ws;
  float* rowsum = (float*)((char*)d_ws + (8u << 20));
  char* bc = (char*)d_ws + (16u << 20);

  cvt_rowsum<<<BATCH, 256, 0, stream>>>(x, xb, rowsum);
  bcompact<<<2048, 256, 0, stream>>>(pw, (int4*)bc);
  hipMemsetAsync(out, 0, (size_t)out_size * sizeof(float), stream);
  dim3 grid(OUT_F / 128, BATCH / 128, KSPLIT);
  qgemm<<<grid, 256, 0, stream>>>(xb, bc, scale, rowsum, out);
}